// Round 24
// baseline (391.703 us; speedup 1.0000x reference)
//
#include <hip/hip_runtime.h>

#define TT 1500
#define BB 96
#define VV 128
#define LGT 256
#define LCAP 512
#define NEGF (-1.0e30f)
#define L2E 1.4426950408889634f
#define LN2F 0.6931471805599453f
#define NW 9    // waves per CTC block (576 threads): oS(<=114)+GH(14) = 128
#define GH 14   // ghost states: 2*HREF=12 < 14
#define HREF 6

// ---------------------------------------------------------------------------
// Kernel 1: greedy decode (unchanged).
// ---------------------------------------------------------------------------
__global__ __launch_bounds__(256) void decode_kernel(
    const float* __restrict__ acts, const int* __restrict__ act_lens,
    int* __restrict__ dec, int* __restrict__ dec_lens) {
  __shared__ int preds[TT];
  __shared__ int sc[256];
  const int b = blockIdx.x;
  const int tid = threadIdx.x;
  const int Tl = act_lens[b];
  for (int t = tid; t < Tl; t += 256) {
    const float4* r4 = (const float4*)(acts + ((size_t)t * BB + b) * VV);
    float best = -3.4e38f;
    int bi = 0;
#pragma unroll
    for (int i = 0; i < VV / 4; i++) {
      float4 v = r4[i];
      if (v.x > best) { best = v.x; bi = 4 * i; }
      if (v.y > best) { best = v.y; bi = 4 * i + 1; }
      if (v.z > best) { best = v.z; bi = 4 * i + 2; }
      if (v.w > best) { best = v.w; bi = 4 * i + 3; }
    }
    preds[t] = bi;
  }
  __syncthreads();

  int pv[6];
  bool fl[6];
  int cnt = 0;
#pragma unroll
  for (int j = 0; j < 6; j++) {
    int t = tid * 6 + j;
    bool valid = t < Tl;
    int p = valid ? preds[t] : 0;
    int pr = (t == 0) ? -1 : (valid ? preds[t - 1] : -1);
    bool f = valid && (p != 0) && (p != pr);
    pv[j] = p;
    fl[j] = f;
    cnt += f;
  }
  sc[tid] = cnt;
  __syncthreads();
  for (int off = 1; off < 256; off <<= 1) {
    int v = sc[tid];
    if (tid >= off) v += sc[tid - off];
    __syncthreads();
    sc[tid] = v;
    __syncthreads();
  }
  int pos = sc[tid] - cnt;  // exclusive prefix
  int total = sc[255];
  int* db = dec + (size_t)b * LCAP;
#pragma unroll
  for (int j = 0; j < 6; j++) {
    if (fl[j]) {
      if (pos < LCAP) db[pos] = pv[j];
      pos++;
    }
  }
  if (tid == 0) {
    if (total == 0) db[0] = 0;
    dec_lens[b] = max(1, min(total, LCAP));
  }
}

// ---------------------------------------------------------------------------
// Kernel 2: CTC. Math = r20's proven best (334us, absmax 0.0). GEOMETRY
// CHANGE: NW 11->9 (576 thr; 18% less issued work since every wave executes
// full 64-lane steps), enabled by HREF 16->6 with GH 34->14 (refresh
// barriers measured ~free in r19/r20: 250 vs 94 barriers was 335 vs 334).
// oS<=114, 114+14 = 128 = exact lane capacity. 6-slot prefetch ring.
// ---------------------------------------------------------------------------
__device__ __forceinline__ float shr1_negf(float x) {
  // lane i <- lane i-1's x; lane 0 <- NEGF.  DPP ctrl 0x138 = wave_shr:1.
  int r = __builtin_amdgcn_update_dpp(__float_as_int(NEGF), __float_as_int(x),
                                      0x138, 0xf, 0xf, false);
  return __int_as_float(r);
}

// log2(1+x) for x in [0,1]; poly only (no trans), Estrin form. err < 1e-4.
__device__ __forceinline__ float log1p2f(float x) {
  float w = __builtin_fmaf(x, 0.6666666666666666f, -0.3333333333333333f);
  float w2 = w * w;
  float wl = w * L2E;
  float P01 = __builtin_fmaf(w, -0.5f, 1.0f);
  float P23 = __builtin_fmaf(w, -0.25f, 0.3333333333333333f);
  float P45 = __builtin_fmaf(w, -0.16666666666666666f, 0.2f);
  float w4 = w2 * w2;
  float p = __builtin_fmaf(w2, P23, P01);
  p = __builtin_fmaf(w4, P45, p);
  // log2(1+x) = p*w*L2E + (log2(3) - 1)
  return __builtin_fmaf(p, wl, 0.5849625007211562f);
}

__global__ __launch_bounds__(64 * NW, 1) void ctc_kernel(
    const float* __restrict__ acts, const int* __restrict__ labels_gt,
    const int* __restrict__ act_lens, const int* __restrict__ label_lens,
    const int* __restrict__ dec, const int* __restrict__ dec_lens,
    float* __restrict__ ends) {
  __shared__ float xall[2][2 * LCAP + 2];  // parity double buffer
  __shared__ float fin[2];
  const int b = blockIdx.x >> 1;
  const int hyp = blockIdx.x & 1;
  const int Tl = act_lens[b];
  const int len = hyp ? dec_lens[b] : label_lens[b];
  const int* lab = hyp ? (dec + (size_t)b * LCAP) : (labels_gt + (size_t)b * LGT);
  const int S = 2 * len + 1;
  const float* act_b = acts + (size_t)b * VV;  // acts[(t*BB + b)*VV + v]
  const int Tlm1 = Tl - 1;

  const int tid = threadIdx.x;
  const int lane = tid & 63, wv = tid >> 6;
  const int oS = 2 * ((S + 2 * NW - 1) / (2 * NW));  // even owned span (<=114)
  const int Se = (S + 1) & ~1;
  const int o0 = min(wv * oS, Se);  // even
  const int o1 = min(o0 + oS, S);
  const int p0 = max(0, o0 - GH);   // even ghost bottom
  const int s0 = p0 + 2 * lane;     // blank state (even)
  const int s1 = s0 + 1;            // label state (odd)

  int e1 = 0;
  bool skip = false;
  if (s1 < S) {
    int li = s1 >> 1;
    e1 = lab[li];
    if (s1 >= 3) skip = (e1 != 0) && (e1 != lab[li - 1]);
  }

  float a0 = NEGF, a1 = NEGF;
  if (wv == 0 && lane == 0) {
    a0 = act_b[0] * L2E;
    a1 = act_b[e1] * L2E;  // S >= 3 always (len >= 1)
  }

  float gL0, gL1, gL2, gL3, gL4, gL5;  // label logits (gather)
  float gB0, gB1, gB2, gB3, gB4, gB5;  // blank logits (uniform)

#define PREF(GL, GB, ROW)                                  \
  {                                                        \
    const float* rp_ = act_b + (size_t)(ROW) * (BB * VV);  \
    GB = rp_[0];                                           \
    GL = rp_[e1];                                          \
  }

#define STEPK(GL, GB)                                                     \
  {                                                                       \
    float pe = shr1_negf(a1);                                             \
    /* u = lse2(a0, pe) via exp2 + poly log1p */                          \
    float m0 = fmaxf(a0, pe);                                             \
    float d0 = fminf(a0, pe) - m0;                                        \
    float u = m0 + log1p2f(__builtin_exp2f(d0));                          \
    /* v = lse2(a1, w), w = skip ? u : a0 */                              \
    float w = skip ? u : a0;                                              \
    float m1 = fmaxf(a1, w);                                              \
    float d1 = fminf(a1, w) - m1;                                         \
    float v = m1 + log1p2f(__builtin_exp2f(d1));                          \
    a0 = __builtin_fmaf(GB, L2E, u);                                      \
    a1 = __builtin_fmaf(GL, L2E, v);                                      \
  }

  // ONE-barrier refresh with parity buffer (vmcnt prefetch stays in flight)
#define REFRESH(K)                                       \
  {                                                      \
    float* xs = xall[(K)&1];                             \
    if (s0 >= o0 && s0 < o1) xs[s0] = a0;                \
    if (s1 >= o0 && s1 < o1) xs[s1] = a1;                \
    asm volatile("s_waitcnt lgkmcnt(0)" ::: "memory");   \
    __builtin_amdgcn_s_barrier();                        \
    if (s0 < o0) {                                       \
      a0 = xs[s0];                                       \
      a1 = (s1 < S) ? xs[s1] : NEGF;                     \
    }                                                    \
  }

  // window step: consume slot, refill same slot with row t+OFF+6
#define W1(OFF, GL, GB)                    \
  STEPK(GL, GB);                           \
  PREF(GL, GB, min(t + (OFF) + 6, Tlm1));

  // tail step: same rotation, with exit checks
#define T1(GL, GB)                         \
  STEPK(GL, GB);                           \
  PREF(GL, GB, min(t + 6, Tlm1));          \
  ++t;                                     \
  if (t >= Tl) break;

  // prologue: slots 0..5 = rows 1..6 (clamped)
  PREF(gL0, gB0, min(1, Tlm1));
  PREF(gL1, gB1, min(2, Tlm1));
  PREF(gL2, gB2, min(3, Tlm1));
  PREF(gL3, gB3, min(4, Tlm1));
  PREF(gL4, gB4, min(5, Tlm1));
  PREF(gL5, gB5, min(6, Tlm1));

  int t = 1, k = 0;
  // main: branch-free 6-step windows; one-barrier refresh per window
  while (t + HREF <= Tl) {
    W1(0, gL0, gB0)
    W1(1, gL1, gB1)
    W1(2, gL2, gB2)
    W1(3, gL3, gB3)
    W1(4, gL4, gB4)
    W1(5, gL5, gB5)
    t += HREF;
    ++k;
    REFRESH(k);
  }
  // tail: <= 5 steps (corruption 2*5=10 < 14), slots aligned (6%6==0)
  while (t < Tl) {
    T1(gL0, gB0)
    T1(gL1, gB1)
    T1(gL2, gB2)
    T1(gL3, gB3)
    T1(gL4, gB4)
    T1(gL5, gB5)
  }
#undef T1
#undef W1
#undef REFRESH
#undef STEPK
#undef PREF

  // end = logaddexp(al[2*len], al[2*len-1]) from owned states
  __syncthreads();
  if (s0 >= o0 && s0 < o1 && s0 == 2 * len) fin[0] = a0;
  if (s1 >= o0 && s1 < o1 && s1 == 2 * len - 1) fin[1] = a1;
  __syncthreads();
  if (tid == 0) {
    float a = fin[0], c = fin[1];
    float m = fmaxf(a, c);
    float e = m + __builtin_log2f(__builtin_exp2f(a - m) + __builtin_exp2f(c - m));
    ends[hyp * BB + b] = e;
  }
}

// ---------------------------------------------------------------------------
// Kernel 3: out[b] = (end_hyp' - end_gt') * ln2 + 1.0  (log2-domain ends)
// ---------------------------------------------------------------------------
__global__ void final_kernel(const float* __restrict__ ends,
                             float* __restrict__ out) {
  int b = threadIdx.x;
  if (b < BB) out[b] = (ends[BB + b] - ends[b]) * LN2F + 1.0f;
}

extern "C" void kernel_launch(void* const* d_in, const int* in_sizes, int n_in,
                              void* d_out, int out_size, void* d_ws,
                              size_t ws_size, hipStream_t stream) {
  const float* acts = (const float*)d_in[0];
  const int* labels = (const int*)d_in[1];
  const int* act_lens = (const int*)d_in[2];
  const int* label_lens = (const int*)d_in[3];
  float* out = (float*)d_out;

  char* ws = (char*)d_ws;
  int* dec = (int*)ws;                                          // B*LCAP ints
  int* dec_lens = (int*)(ws + (size_t)BB * LCAP * 4);           // B ints
  float* ends = (float*)(ws + (size_t)BB * LCAP * 4 + BB * 4);  // 2*B floats

  decode_kernel<<<dim3(BB), dim3(256), 0, stream>>>(acts, act_lens, dec, dec_lens);
  // 80KB dynamic LDS (+8.2KB static): 1 block/CU -> 2.25 waves/SIMD.
  ctc_kernel<<<dim3(2 * BB), dim3(64 * NW), 80 * 1024, stream>>>(
      acts, labels, act_lens, label_lens, dec, dec_lens, ends);
  final_kernel<<<dim3(1), dim3(128), 0, stream>>>(ends, out);
}

// Round 25
// 347.745 us; speedup vs baseline: 1.1264x; 1.1264x over previous
//
#include <hip/hip_runtime.h>

#define TT 1500
#define BB 96
#define VV 128
#define LGT 256
#define LCAP 512
#define NEGF (-1.0e30f)
#define L2E 1.4426950408889634f
#define LN2F 0.6931471805599453f
#define NW 11  // waves per CTC block (704 threads)
#define GH 34  // ghost states: 2*HREF=32 < 34; oS(<=94)+34 <= 128
#define HREF 16

// ---------------------------------------------------------------------------
// Kernel 1: greedy decode.
// ---------------------------------------------------------------------------
__global__ __launch_bounds__(256) void decode_kernel(
    const float* __restrict__ acts, const int* __restrict__ act_lens,
    int* __restrict__ dec, int* __restrict__ dec_lens) {
  __shared__ int preds[TT];
  __shared__ int sc[256];
  const int b = blockIdx.x;
  const int tid = threadIdx.x;
  const int Tl = act_lens[b];
  for (int t = tid; t < Tl; t += 256) {
    const float4* r4 = (const float4*)(acts + ((size_t)t * BB + b) * VV);
    float best = -3.4e38f;
    int bi = 0;
#pragma unroll
    for (int i = 0; i < VV / 4; i++) {
      float4 v = r4[i];
      if (v.x > best) { best = v.x; bi = 4 * i; }
      if (v.y > best) { best = v.y; bi = 4 * i + 1; }
      if (v.z > best) { best = v.z; bi = 4 * i + 2; }
      if (v.w > best) { best = v.w; bi = 4 * i + 3; }
    }
    preds[t] = bi;
  }
  __syncthreads();

  int pv[6];
  bool fl[6];
  int cnt = 0;
#pragma unroll
  for (int j = 0; j < 6; j++) {
    int t = tid * 6 + j;
    bool valid = t < Tl;
    int p = valid ? preds[t] : 0;
    int pr = (t == 0) ? -1 : (valid ? preds[t - 1] : -1);
    bool f = valid && (p != 0) && (p != pr);
    pv[j] = p;
    fl[j] = f;
    cnt += f;
  }
  sc[tid] = cnt;
  __syncthreads();
  for (int off = 1; off < 256; off <<= 1) {
    int v = sc[tid];
    if (tid >= off) v += sc[tid - off];
    __syncthreads();
    sc[tid] = v;
    __syncthreads();
  }
  int pos = sc[tid] - cnt;  // exclusive prefix
  int total = sc[255];
  int* db = dec + (size_t)b * LCAP;
#pragma unroll
  for (int j = 0; j < 6; j++) {
    if (fl[j]) {
      if (pos < LCAP) db[pos] = pv[j];
      pos++;
    }
  }
  if (tid == 0) {
    if (total == 0) db[0] = 0;
    dec_lens[b] = max(1, min(total, LCAP));
  }
}

// ---------------------------------------------------------------------------
// Kernel 2: CTC — best measured configuration (334us ctc, absmax 0.0).
// Log2-domain lse2 recursion, R=2 even/odd lane-major layout, DPP rotate,
// NW=11 (2.75 waves/SIMD, 1 block/CU via 80KB dyn LDS), branch-free 16-step
// windows, 8-slot register prefetch ring, one-barrier parity refresh.
// ---------------------------------------------------------------------------
__device__ __forceinline__ float shr1_negf(float x) {
  // lane i <- lane i-1's x; lane 0 <- NEGF.  DPP ctrl 0x138 = wave_shr:1.
  int r = __builtin_amdgcn_update_dpp(__float_as_int(NEGF), __float_as_int(x),
                                      0x138, 0xf, 0xf, false);
  return __int_as_float(r);
}

// log2(1+x) for x in [0,1]; poly only (no trans). abs err < 1e-4.
__device__ __forceinline__ float log1p2f(float x) {
  float w = __builtin_fmaf(x, 0.6666666666666666f, -0.3333333333333333f);
  float p = -0.16666666666666666f;               // -1/6
  p = __builtin_fmaf(p, w, 0.2f);                // +1/5
  p = __builtin_fmaf(p, w, -0.25f);              // -1/4
  p = __builtin_fmaf(p, w, 0.3333333333333333f); // +1/3
  p = __builtin_fmaf(p, w, -0.5f);               // -1/2
  p = __builtin_fmaf(p, w, 1.0f);                // +1
  return __builtin_fmaf(p * w, L2E, 0.5849625007211562f);  // + log2(3)-1
}

__global__ __launch_bounds__(64 * NW, 1) void ctc_kernel(
    const float* __restrict__ acts, const int* __restrict__ labels_gt,
    const int* __restrict__ act_lens, const int* __restrict__ label_lens,
    const int* __restrict__ dec, const int* __restrict__ dec_lens,
    float* __restrict__ ends) {
  __shared__ float xall[2][2 * LCAP + 2];  // parity double buffer
  __shared__ float fin[2];
  const int b = blockIdx.x >> 1;
  const int hyp = blockIdx.x & 1;
  const int Tl = act_lens[b];
  const int len = hyp ? dec_lens[b] : label_lens[b];
  const int* lab = hyp ? (dec + (size_t)b * LCAP) : (labels_gt + (size_t)b * LGT);
  const int S = 2 * len + 1;
  const float* act_b = acts + (size_t)b * VV;  // acts[(t*BB + b)*VV + v]
  const int Tlm1 = Tl - 1;

  const int tid = threadIdx.x;
  const int lane = tid & 63, wv = tid >> 6;
  const int oS = 2 * ((S + 2 * NW - 1) / (2 * NW));  // even owned span (<=94)
  const int Se = (S + 1) & ~1;
  const int o0 = min(wv * oS, Se);  // even
  const int o1 = min(o0 + oS, S);
  const int p0 = max(0, o0 - GH);   // even ghost bottom
  const int s0 = p0 + 2 * lane;     // blank state (even)
  const int s1 = s0 + 1;            // label state (odd)

  int e1 = 0;
  bool skip = false;
  if (s1 < S) {
    int li = s1 >> 1;
    e1 = lab[li];
    if (s1 >= 3) skip = (e1 != 0) && (e1 != lab[li - 1]);
  }

  float a0 = NEGF, a1 = NEGF;
  if (wv == 0 && lane == 0) {
    a0 = act_b[0] * L2E;
    a1 = act_b[e1] * L2E;  // S >= 3 always (len >= 1)
  }

  float gL0, gL1, gL2, gL3, gL4, gL5, gL6, gL7;  // label logits (gather)
  float gB0, gB1, gB2, gB3, gB4, gB5, gB6, gB7;  // blank logits (uniform)

#define PREF(GL, GB, ROW)                                  \
  {                                                        \
    const float* rp_ = act_b + (size_t)(ROW) * (BB * VV);  \
    GB = rp_[0];                                           \
    GL = rp_[e1];                                          \
  }

#define STEPK(GL, GB)                                                     \
  {                                                                       \
    float pe = shr1_negf(a1);                                             \
    /* u = lse2(a0, pe) via exp2 + poly log1p */                          \
    float m0 = fmaxf(a0, pe);                                             \
    float d0 = fminf(a0, pe) - m0;                                        \
    float u = m0 + log1p2f(__builtin_exp2f(d0));                          \
    /* v = lse2(a1, w), w = skip ? u : a0 */                              \
    float w = skip ? u : a0;                                              \
    float m1 = fmaxf(a1, w);                                              \
    float d1 = fminf(a1, w) - m1;                                         \
    float v = m1 + log1p2f(__builtin_exp2f(d1));                          \
    a0 = __builtin_fmaf(GB, L2E, u);                                      \
    a1 = __builtin_fmaf(GL, L2E, v);                                      \
  }

  // ONE-barrier refresh with parity buffer (vmcnt prefetch stays in flight)
#define REFRESH(K)                                       \
  {                                                      \
    float* xs = xall[(K)&1];                             \
    if (s0 >= o0 && s0 < o1) xs[s0] = a0;                \
    if (s1 >= o0 && s1 < o1) xs[s1] = a1;                \
    asm volatile("s_waitcnt lgkmcnt(0)" ::: "memory");   \
    __builtin_amdgcn_s_barrier();                        \
    if (s0 < o0) {                                       \
      a0 = xs[s0];                                       \
      a1 = (s1 < S) ? xs[s1] : NEGF;                     \
    }                                                    \
  }

  // window step: consume slot, refill same slot with row t+OFF+8
#define W1(OFF, GL, GB)                    \
  STEPK(GL, GB);                           \
  PREF(GL, GB, min(t + (OFF) + 8, Tlm1));

  // tail step: same rotation, with exit checks
#define T1(GL, GB)                         \
  STEPK(GL, GB);                           \
  PREF(GL, GB, min(t + 8, Tlm1));          \
  ++t;                                     \
  if (t >= Tl) break;

  // prologue: slots 0..7 = rows 1..8 (clamped)
  PREF(gL0, gB0, min(1, Tlm1));
  PREF(gL1, gB1, min(2, Tlm1));
  PREF(gL2, gB2, min(3, Tlm1));
  PREF(gL3, gB3, min(4, Tlm1));
  PREF(gL4, gB4, min(5, Tlm1));
  PREF(gL5, gB5, min(6, Tlm1));
  PREF(gL6, gB6, min(7, Tlm1));
  PREF(gL7, gB7, min(8, Tlm1));

  int t = 1, k = 0;
  // main: branch-free 16-step windows; one-barrier refresh per window
  while (t + HREF <= Tl) {
    W1(0, gL0, gB0)
    W1(1, gL1, gB1)
    W1(2, gL2, gB2)
    W1(3, gL3, gB3)
    W1(4, gL4, gB4)
    W1(5, gL5, gB5)
    W1(6, gL6, gB6)
    W1(7, gL7, gB7)
    W1(8, gL0, gB0)
    W1(9, gL1, gB1)
    W1(10, gL2, gB2)
    W1(11, gL3, gB3)
    W1(12, gL4, gB4)
    W1(13, gL5, gB5)
    W1(14, gL6, gB6)
    W1(15, gL7, gB7)
    t += HREF;
    ++k;
    REFRESH(k);
  }
  // tail: <= 15 steps (ghost covers 2*15=30 < 34), slots aligned (16%8==0)
  while (t < Tl) {
    T1(gL0, gB0)
    T1(gL1, gB1)
    T1(gL2, gB2)
    T1(gL3, gB3)
    T1(gL4, gB4)
    T1(gL5, gB5)
    T1(gL6, gB6)
    T1(gL7, gB7)
  }
#undef T1
#undef W1
#undef REFRESH
#undef STEPK
#undef PREF

  // end = logaddexp(al[2*len], al[2*len-1]) from owned states
  __syncthreads();
  if (s0 >= o0 && s0 < o1 && s0 == 2 * len) fin[0] = a0;
  if (s1 >= o0 && s1 < o1 && s1 == 2 * len - 1) fin[1] = a1;
  __syncthreads();
  if (tid == 0) {
    float a = fin[0], c = fin[1];
    float m = fmaxf(a, c);
    float e = m + __builtin_log2f(__builtin_exp2f(a - m) + __builtin_exp2f(c - m));
    ends[hyp * BB + b] = e;
  }
}

// ---------------------------------------------------------------------------
// Kernel 3: out[b] = (end_hyp' - end_gt') * ln2 + 1.0  (log2-domain ends)
// ---------------------------------------------------------------------------
__global__ void final_kernel(const float* __restrict__ ends,
                             float* __restrict__ out) {
  int b = threadIdx.x;
  if (b < BB) out[b] = (ends[BB + b] - ends[b]) * LN2F + 1.0f;
}

extern "C" void kernel_launch(void* const* d_in, const int* in_sizes, int n_in,
                              void* d_out, int out_size, void* d_ws,
                              size_t ws_size, hipStream_t stream) {
  const float* acts = (const float*)d_in[0];
  const int* labels = (const int*)d_in[1];
  const int* act_lens = (const int*)d_in[2];
  const int* label_lens = (const int*)d_in[3];
  float* out = (float*)d_out;

  char* ws = (char*)d_ws;
  int* dec = (int*)ws;                                          // B*LCAP ints
  int* dec_lens = (int*)(ws + (size_t)BB * LCAP * 4);           // B ints
  float* ends = (float*)(ws + (size_t)BB * LCAP * 4 + BB * 4);  // 2*B floats

  decode_kernel<<<dim3(BB), dim3(256), 0, stream>>>(acts, act_lens, dec, dec_lens);
  // 80KB dynamic LDS (+8.2KB static): 1 block/CU -> 2.75 waves/SIMD.
  ctc_kernel<<<dim3(2 * BB), dim3(64 * NW), 80 * 1024, stream>>>(
      acts, labels, act_lens, label_lens, dec, dec_lens, ends);
  final_kernel<<<dim3(1), dim3(128), 0, stream>>>(ends, out);
}